// Round 3
// baseline (169.724 us; speedup 1.0000x reference)
//
#include <hip/hip_runtime.h>
#include <math.h>

#define CCH   256
#define NPIX  4096
#define BATCH 4

typedef __attribute__((ext_vector_type(8))) short s16x8;
typedef __attribute__((ext_vector_type(4))) float f32x4;

__device__ __forceinline__ unsigned short f2bf(float f) {
    unsigned int u = __float_as_uint(f);
    u += 0x7fff + ((u >> 16) & 1);          // RNE; values are finite
    return (unsigned short)(u >> 16);
}
__device__ __forceinline__ float bf2f(unsigned short h) {
    return __uint_as_float(((unsigned int)h) << 16);
}

// q/k frag (16x16x32 A/B layout), element for (pixel n, dim d):
//   tile = n>>4, lane = (d>>3)*16 + (n&15), elem = d&7
__device__ __forceinline__ size_t qk_addr(int b, int n, int d) {
    return ((((size_t)b * 256 + (n >> 4)) * 64 + ((d >> 3) << 4) + (n & 15)) << 3) + (d & 7);
}
// v frag: standard A-layout for PV; k = j (32-step), m = c (16-tile):
//   tile = (b, j64, c-tile, jj-half), lane = ((j&31)>>3)*16 + (c&15), elem = j&7
__device__ __forceinline__ size_t v_addr(int b, int j, int c) {
    return ((((((size_t)b * 64 + (j >> 6)) * 16 + (c >> 4)) * 2 + ((j >> 5) & 1)) * 64
            + (((j >> 3) & 3) << 4) + (c & 15)) << 3) + (j & 7);
}

// ---------------- W -> A-frag bf16 (hi/lo for q,k; hi for v), once ----------------
__global__ __launch_bounds__(64) void wcast_kernel(
    const float* __restrict__ Wq, const float* __restrict__ bq,
    const float* __restrict__ Wk, const float* __restrict__ bk,
    const float* __restrict__ Wv, const float* __restrict__ bv,
    unsigned short* __restrict__ wfh, unsigned short* __restrict__ wfl,
    float* __restrict__ bias_ws)
{
    const int rt = blockIdx.x;
    const int lane = threadIdx.x, l15 = lane & 15, quad = lane >> 4;
    const float *Ws, *bs; int roff; float scale = 1.0f;
    if (rt < 2)      { Ws = Wq; bs = bq; roff = rt * 16;      scale = 1.44269504f; }
    else if (rt < 4) { Ws = Wk; bs = bk; roff = (rt - 2) * 16; }
    else             { Ws = Wv; bs = bv; roff = (rt - 4) * 16; }

    const float* wrow = Ws + (size_t)(roff + l15) * CCH + quad * 8;
    for (int kb = 0; kb < 8; ++kb) {
        s16x8 h, l;
        #pragma unroll
        for (int d = 0; d < 8; ++d) {
            float wv = wrow[kb * 32 + d] * scale;
            unsigned short hh = f2bf(wv);
            h[d] = (short)hh;
            l[d] = (short)f2bf(wv - bf2f(hh));
        }
        *(s16x8*)&wfh[(((size_t)rt * 8 + kb) * 64 + lane) * 8] = h;
        if (rt < 4) *(s16x8*)&wfl[(((size_t)rt * 8 + kb) * 64 + lane) * 8] = l;
    }
    if (lane < 16) bias_ws[rt * 16 + lane] = bs[roff + lane] * scale;
}

// ---------------- fused cast+projection ----------------
__global__ __launch_bounds__(256, 4) void proj_kernel(
    const float* __restrict__ x,
    const unsigned short* __restrict__ wfh, const unsigned short* __restrict__ wfl,
    const float* __restrict__ bias_ws,
    unsigned short* __restrict__ q_hi, unsigned short* __restrict__ q_lo,
    unsigned short* __restrict__ k_hi, unsigned short* __restrict__ k_lo,
    unsigned short* __restrict__ v_frag)
{
    const int t = threadIdx.x;
    const int rh = t >> 6, lane = t & 63, l15 = lane & 15, quad = lane >> 4;
    const int b = blockIdx.y;
    const int nt = blockIdx.x;

    const float* xb = x + (size_t)b * CCH * NPIX + nt * 16 + l15;
    s16x8 xh[8], xl[8];
    #pragma unroll
    for (int kb = 0; kb < 8; ++kb) {
        s16x8 vh, vl;
        #pragma unroll
        for (int d = 0; d < 8; ++d) {
            float xv = xb[(size_t)(kb * 32 + quad * 8 + d) * NPIX];
            unsigned short h = f2bf(xv);
            vh[d] = (short)h;
            vl[d] = (short)f2bf(xv - bf2f(h));
        }
        xh[kb] = vh; xl[kb] = vl;
    }

    const int n = nt * 16 + l15;
    #pragma unroll 1
    for (int tt = 0; tt < 5; ++tt) {
        const int rt = rh * 5 + tt;
        if (rt < 4) {
            f32x4 acc0 = {0.f, 0.f, 0.f, 0.f};
            f32x4 acc1 = {0.f, 0.f, 0.f, 0.f};
            #pragma unroll
            for (int kb = 0; kb < 8; ++kb) {
                s16x8 ah = *(const s16x8*)&wfh[(((size_t)rt * 8 + kb) * 64 + lane) * 8];
                s16x8 al = *(const s16x8*)&wfl[(((size_t)rt * 8 + kb) * 64 + lane) * 8];
                acc0 = __builtin_amdgcn_mfma_f32_16x16x32_bf16(ah, xh[kb], acc0, 0, 0, 0);
                acc1 = __builtin_amdgcn_mfma_f32_16x16x32_bf16(ah, xl[kb], acc1, 0, 0, 0);
                acc1 = __builtin_amdgcn_mfma_f32_16x16x32_bf16(al, xh[kb], acc1, 0, 0, 0);
            }
            #pragma unroll
            for (int rr = 0; rr < 4; ++rr) {
                const int rloc = quad * 4 + rr;
                const float val = acc0[rr] + acc1[rr] + bias_ws[rt * 16 + rloc];
                unsigned short h = f2bf(val);
                unsigned short l = f2bf(val - bf2f(h));
                if (rt < 2) {
                    const size_t a = qk_addr(b, n, rt * 16 + rloc);
                    q_hi[a] = h; q_lo[a] = l;
                } else {
                    const size_t a = qk_addr(b, n, (rt - 2) * 16 + rloc);
                    k_hi[a] = h; k_lo[a] = l;
                }
            }
        } else {
            f32x4 acc = {0.f, 0.f, 0.f, 0.f};
            #pragma unroll
            for (int kb = 0; kb < 8; ++kb) {
                s16x8 ah = *(const s16x8*)&wfh[(((size_t)rt * 8 + kb) * 64 + lane) * 8];
                acc = __builtin_amdgcn_mfma_f32_16x16x32_bf16(ah, xh[kb], acc, 0, 0, 0);
            }
            #pragma unroll
            for (int rr = 0; rr < 4; ++rr) {
                const int rloc = quad * 4 + rr;
                const float val = acc[rr] + bias_ws[rt * 16 + rloc];
                v_frag[v_addr(b, n, (rt - 4) * 16 + rloc)] = f2bf(val);
            }
        }
    }
}

// ---------------- flash attention: merged 1024-thread blocks ----------------
// 256 blocks (1/CU) x 16 waves = (ih 0..1, jh 0..1, ch 0..3).
// KEY CHANGE vs 63.8us version: the barrier is moved from mid-window (between
// QK(t+1) and PV(t)) to END of window.  The barrier only protects the p_lds
// double-buffer handoff; placing it last puts PV(t)'s 16 independent MFMAs in
// the same scheduling region as QK(t+1)'s serial MFMA->exp2->pack chain, so
// the compiler interleaves MFMA and VALU work instead of phase-alternating
// (time was sum-of-pipes, target is max-of-pipes).  v4-7 loads also gain
// ~400cy cover (were issued post-barrier with ~60cy).
#define BARRIER_LGKM() do { \
    asm volatile("s_waitcnt lgkmcnt(0)" ::: "memory"); \
    __builtin_amdgcn_s_barrier(); \
    asm volatile("" ::: "memory"); \
} while (0)

#define QK_STEP(KFH, KFL, BUFC) do { \
    f32x4 a0 = __builtin_amdgcn_mfma_f32_16x16x32_bf16((KFH), qfl0, (f32x4){0.f,0.f,0.f,0.f}, 0, 0, 0); \
    a0 = __builtin_amdgcn_mfma_f32_16x16x32_bf16((KFL), qfh0, a0, 0, 0, 0); \
    a0 = __builtin_amdgcn_mfma_f32_16x16x32_bf16((KFH), qfh0, a0, 0, 0, 0); \
    f32x4 a1 = __builtin_amdgcn_mfma_f32_16x16x32_bf16((KFH), qfl1, (f32x4){0.f,0.f,0.f,0.f}, 0, 0, 0); \
    a1 = __builtin_amdgcn_mfma_f32_16x16x32_bf16((KFL), qfh1, a1, 0, 0, 0); \
    a1 = __builtin_amdgcn_mfma_f32_16x16x32_bf16((KFH), qfh1, a1, 0, 0, 0); \
    unsigned int u0 = __float_as_uint(__builtin_exp2f(a0[0])) + 0x8000u; \
    unsigned int u1 = __float_as_uint(__builtin_exp2f(a0[1])) + 0x8000u; \
    unsigned int u2 = __float_as_uint(__builtin_exp2f(a0[2])) + 0x8000u; \
    unsigned int u3 = __float_as_uint(__builtin_exp2f(a0[3])) + 0x8000u; \
    uint2 pv0; \
    pv0.x = __builtin_amdgcn_perm(u1, u0, 0x07060302u); \
    pv0.y = __builtin_amdgcn_perm(u3, u2, 0x07060302u); \
    *(uint2*)&shm.p[ih][jh][BUFC][0 * 2 + pfrag_jj][(prow * 16 + l15) * 8 + pcol] = pv0; \
    u0 = __float_as_uint(__builtin_exp2f(a1[0])) + 0x8000u; \
    u1 = __float_as_uint(__builtin_exp2f(a1[1])) + 0x8000u; \
    u2 = __float_as_uint(__builtin_exp2f(a1[2])) + 0x8000u; \
    u3 = __float_as_uint(__builtin_exp2f(a1[3])) + 0x8000u; \
    uint2 pv1; \
    pv1.x = __builtin_amdgcn_perm(u1, u0, 0x07060302u); \
    pv1.y = __builtin_amdgcn_perm(u3, u2, 0x07060302u); \
    *(uint2*)&shm.p[ih][jh][BUFC][1 * 2 + pfrag_jj][(prow * 16 + l15) * 8 + pcol] = pv1; \
} while (0)

// One pipelined iteration.  T: current j-step; BUFC: its p buffer (T&1).
// KU_*: K regs holding tile T+1 (consumed by QK).  KL_*: regs to prefetch
// tile T+2 into.  DO_QK: whether a T+1 tile exists.
// Hazard audit for the single end-of-window barrier:
//   - pf(T) reads buf(T): written by QK(T) last window, drained at that
//     window's end barrier.  OK.
//   - QK(T+1) writes buf(T)^1: last read as pf(T-1) two windows back, that
//     read drained at the T-1 end barrier.  OK.
//   - pf(T+1) reads (next window) vs QK(T+1) writes (this window): separated
//     by this window's end barrier + lgkmcnt(0).  OK.
#define ATTN_BODY(T, BUFC, KU_H, KU_L, KL_H, KL_L, DO_QK) do { \
    const int jt = jh * 32 + (T); \
    /* P(T) frag reads -- consumed by lacc/PV late in this window */ \
    const s16x8 pf0 = *(const s16x8*)&shm.p[ih][jh][BUFC][0][lane * 8]; \
    const s16x8 pf1 = *(const s16x8*)&shm.p[ih][jh][BUFC][1][lane * 8]; \
    const s16x8 pf2 = *(const s16x8*)&shm.p[ih][jh][BUFC][2][lane * 8]; \
    const s16x8 pf3 = *(const s16x8*)&shm.p[ih][jh][BUFC][3][lane * 8]; \
    /* V(T) loads -- covered by QK(T+1)+exp chain before PV consumes them */ \
    const size_t vbase = (((size_t)jt * 16 + ch * 4) * 2) * 512; \
    const s16x8 v0 = *(const s16x8*)(vb + vbase); \
    const s16x8 v1 = *(const s16x8*)(vb + vbase + 512); \
    const s16x8 v2 = *(const s16x8*)(vb + vbase + 1024); \
    const s16x8 v3 = *(const s16x8*)(vb + vbase + 1536); \
    if (DO_QK) { QK_STEP(KU_H, KU_L, (BUFC) ^ 1); } \
    /* K(T+2) prefetch (clamped dummy at tail; value unused) */ \
    { \
        const int tpp = ((T) + 2 < 32) ? (T) + 2 : 0; \
        const size_t koff = (size_t)((jh * 32 + tpp) * 4 + ch) * 512; \
        KL_H = *(const s16x8*)(khb + koff); \
        KL_L = *(const s16x8*)(klb + koff); \
    } \
    /* denominator partials: ch0 -> it0 (pf0,pf1), ch1 -> it1 (pf2,pf3) */ \
    if (ch == 0) { \
        lacc = __builtin_amdgcn_mfma_f32_16x16x32_bf16(ones, pf0, lacc, 0, 0, 0); \
        lacc = __builtin_amdgcn_mfma_f32_16x16x32_bf16(ones, pf1, lacc, 0, 0, 0); \
    } else if (ch == 1) { \
        lacc = __builtin_amdgcn_mfma_f32_16x16x32_bf16(ones, pf2, lacc, 0, 0, 0); \
        lacc = __builtin_amdgcn_mfma_f32_16x16x32_bf16(ones, pf3, lacc, 0, 0, 0); \
    } \
    /* V(T) second half -- now also pre-barrier, ~400cy cover */ \
    const s16x8 v4 = *(const s16x8*)(vb + vbase + 2048); \
    const s16x8 v5 = *(const s16x8*)(vb + vbase + 2560); \
    const s16x8 v6 = *(const s16x8*)(vb + vbase + 3072); \
    const s16x8 v7 = *(const s16x8*)(vb + vbase + 3584); \
    __builtin_amdgcn_s_setprio(1); \
    acc[0] = __builtin_amdgcn_mfma_f32_16x16x32_bf16(v0, pf0, acc[0], 0, 0, 0); \
    acc[0] = __builtin_amdgcn_mfma_f32_16x16x32_bf16(v1, pf1, acc[0], 0, 0, 0); \
    acc[1] = __builtin_amdgcn_mfma_f32_16x16x32_bf16(v0, pf2, acc[1], 0, 0, 0); \
    acc[1] = __builtin_amdgcn_mfma_f32_16x16x32_bf16(v1, pf3, acc[1], 0, 0, 0); \
    acc[2] = __builtin_amdgcn_mfma_f32_16x16x32_bf16(v2, pf0, acc[2], 0, 0, 0); \
    acc[2] = __builtin_amdgcn_mfma_f32_16x16x32_bf16(v3, pf1, acc[2], 0, 0, 0); \
    acc[3] = __builtin_amdgcn_mfma_f32_16x16x32_bf16(v2, pf2, acc[3], 0, 0, 0); \
    acc[3] = __builtin_amdgcn_mfma_f32_16x16x32_bf16(v3, pf3, acc[3], 0, 0, 0); \
    acc[4] = __builtin_amdgcn_mfma_f32_16x16x32_bf16(v4, pf0, acc[4], 0, 0, 0); \
    acc[4] = __builtin_amdgcn_mfma_f32_16x16x32_bf16(v5, pf1, acc[4], 0, 0, 0); \
    acc[5] = __builtin_amdgcn_mfma_f32_16x16x32_bf16(v4, pf2, acc[5], 0, 0, 0); \
    acc[5] = __builtin_amdgcn_mfma_f32_16x16x32_bf16(v5, pf3, acc[5], 0, 0, 0); \
    acc[6] = __builtin_amdgcn_mfma_f32_16x16x32_bf16(v6, pf0, acc[6], 0, 0, 0); \
    acc[6] = __builtin_amdgcn_mfma_f32_16x16x32_bf16(v7, pf1, acc[6], 0, 0, 0); \
    acc[7] = __builtin_amdgcn_mfma_f32_16x16x32_bf16(v6, pf2, acc[7], 0, 0, 0); \
    acc[7] = __builtin_amdgcn_mfma_f32_16x16x32_bf16(v7, pf3, acc[7], 0, 0, 0); \
    __builtin_amdgcn_s_setprio(0); \
    BARRIER_LGKM(); \
} while (0)

union AttnShMem {
    unsigned short p[2][2][2][4][512];   // [ih][jh][buf][frag][lane*8] = 32 KB
    f32x4 comb[2][2][4][2][64];          // [ih][jh_src][ch][ct-slot][lane] = 32 KB (epilogue only)
};

__global__ __launch_bounds__(1024, 4) void attn_kernel(
    const unsigned short* __restrict__ q_hi, const unsigned short* __restrict__ q_lo,
    const unsigned short* __restrict__ k_hi, const unsigned short* __restrict__ k_lo,
    const unsigned short* __restrict__ v_frag,
    const float* __restrict__ x, float* __restrict__ out)
{
    __shared__ AttnShMem shm;
    __shared__ float lds_l[2][2][2][16];      // [ih][jh_src][ch01][lane]

    const int t = threadIdx.x;
    const int w = t >> 6, lane = t & 63, l15 = lane & 15, quad = lane >> 4;
    const int ih = w >> 3, jh = (w >> 2) & 1, ch = w & 3;

    const int f = blockIdx.x;                 // 0..255; XCD-pair per batch
    const int xcd = f & 7;
    const int b = xcd >> 1;
    const int ib = ((xcd & 1) << 5) + (f >> 3);   // i-block 0..63 (64 pixels)

    s16x8 qfh0, qfl0, qfh1, qfl1;
    {
        const int ti0 = ib * 4 + ih * 2;
        const size_t qo0 = ((size_t)b * 256 + ti0 + 0) * 512 + (size_t)lane * 8;
        const size_t qo1 = ((size_t)b * 256 + ti0 + 1) * 512 + (size_t)lane * 8;
        qfh0 = *(const s16x8*)(q_hi + qo0);  qfl0 = *(const s16x8*)(q_lo + qo0);
        qfh1 = *(const s16x8*)(q_hi + qo1);  qfl1 = *(const s16x8*)(q_lo + qo1);
    }

    const s16x8 ones = { (short)0x3F80, (short)0x3F80, (short)0x3F80, (short)0x3F80,
                         (short)0x3F80, (short)0x3F80, (short)0x3F80, (short)0x3F80 };

    f32x4 acc[8];                             // [ct*2+it], constant indices only
    #pragma unroll
    for (int i = 0; i < 8; ++i) acc[i] = (f32x4){0.f, 0.f, 0.f, 0.f};
    f32x4 lacc = {0.f, 0.f, 0.f, 0.f};

    const unsigned short* khb = k_hi + (size_t)b * 131072 + (size_t)lane * 8;
    const unsigned short* klb = k_lo + (size_t)b * 131072 + (size_t)lane * 8;
    const unsigned short* vb  = v_frag + (size_t)b * 1048576 + (size_t)lane * 8;

    const int prow = ((ch & 1) << 1) + (quad >> 1);
    const int pcol = ((quad & 1) << 2);
    const int pfrag_jj = ch >> 1;

    // ---- prologue: K(0) -> QK(0) -> P(0) in buf0; prefetch K(1) ----
    s16x8 ka_h, ka_l, kb_h, kb_l;
    {
        const size_t k0 = (size_t)((jh * 32 + 0) * 4 + ch) * 512;
        ka_h = *(const s16x8*)(khb + k0);
        ka_l = *(const s16x8*)(klb + k0);
    }
    QK_STEP(ka_h, ka_l, 0);
    {
        const size_t k1 = (size_t)((jh * 32 + 1) * 4 + ch) * 512;
        ka_h = *(const s16x8*)(khb + k1);
        ka_l = *(const s16x8*)(klb + k1);
    }
    BARRIER_LGKM();

    #pragma unroll 1
    for (int t2 = 0; t2 < 16; ++t2) {
        ATTN_BODY(2 * t2,     0, ka_h, ka_l, kb_h, kb_l, 1);
        ATTN_BODY(2 * t2 + 1, 1, kb_h, kb_l, ka_h, ka_l, (t2 < 15));
    }

    // ---- epilogue: 2-pass comb exchange overlaid on p_lds (dead after loop) ----
    // Safe: all p reads complete before the final BARRIER_LGKM (lgkmcnt(0)),
    // and every wave has passed that barrier before reaching here.
    if (ch < 2 && lane < 16) lds_l[ih][jh][ch][lane] = lacc[0];
    // pass A: ct 0,1
    if (jh == 0) { shm.comb[ih][0][ch][0][lane] = acc[1]; shm.comb[ih][0][ch][1][lane] = acc[3]; }
    else         { shm.comb[ih][1][ch][0][lane] = acc[0]; shm.comb[ih][1][ch][1][lane] = acc[2]; }
    __syncthreads();
    const float linv = 1.f / (lds_l[ih][0][jh][l15] + lds_l[ih][1][jh][l15]);
    const int ibase = (ib * 4 + ih * 2 + jh) * 16 + l15;
    {
        f32x4 a0 = (jh == 0) ? acc[0] : acc[1];
        f32x4 a1 = (jh == 0) ? acc[2] : acc[3];
        a0 += shm.comb[ih][1 - jh][ch][0][lane];
        a1 += shm.comb[ih][1 - jh][ch][1][lane];
        #pragma unroll
        for (int rr = 0; rr < 4; ++rr) {
            const int c0 = ch * 64 + 0 * 16 + quad * 4 + rr;
            const int c1 = ch * 64 + 1 * 16 + quad * 4 + rr;
            const size_t i0 = ((size_t)b * CCH + c0) * NPIX + ibase;
            const size_t i1 = ((size_t)b * CCH + c1) * NPIX + ibase;
            out[i0] = a0[rr] * linv + x[i0];
            out[i1] = a1[rr] * linv + x[i1];
        }
    }
    __syncthreads();
    // pass B: ct 2,3
    if (jh == 0) { shm.comb[ih][0][ch][0][lane] = acc[5]; shm.comb[ih][0][ch][1][lane] = acc[7]; }
    else         { shm.comb[ih][1][ch][0][lane] = acc[4]; shm.comb[ih][1][ch][1][lane] = acc[6]; }
    __syncthreads();
    {
        f32x4 a2 = (jh == 0) ? acc[4] : acc[5];
        f32x4 a3 = (jh == 0) ? acc[6] : acc[7];
        a2 += shm.comb[ih][1 - jh][ch][0][lane];
        a3 += shm.comb[ih][1 - jh][ch][1][lane];
        #pragma unroll
        for (int rr = 0; rr < 4; ++rr) {
            const int c2 = ch * 64 + 2 * 16 + quad * 4 + rr;
            const int c3 = ch * 64 + 3 * 16 + quad * 4 + rr;
            const size_t i2 = ((size_t)b * CCH + c2) * NPIX + ibase;
            const size_t i3 = ((size_t)b * CCH + c3) * NPIX + ibase;
            out[i2] = a2[rr] * linv + x[i2];
            out[i3] = a3[rr] * linv + x[i3];
        }
    }
}

extern "C" void kernel_launch(void* const* d_in, const int* in_sizes, int n_in,
                              void* d_out, int out_size, void* d_ws, size_t ws_size,
                              hipStream_t stream) {
    const float* x  = (const float*)d_in[0];
    const float* Wq = (const float*)d_in[1];
    const float* bq = (const float*)d_in[2];
    const float* Wk = (const float*)d_in[3];
    const float* bk = (const float*)d_in[4];
    const float* Wv = (const float*)d_in[5];
    const float* bv = (const float*)d_in[6];
    float* out = (float*)d_out;

    unsigned short* ws = (unsigned short*)d_ws;
    unsigned short* q_hi   = ws;                 //   524,288
    unsigned short* q_lo   = ws + 524288;        //   524,288
    unsigned short* k_hi   = ws + 1048576;       //   524,288
    unsigned short* k_lo   = ws + 1572864;       //   524,288
    unsigned short* v_frag = ws + 2097152;       // 4,194,304
    unsigned short* wfh    = ws + 6291456;       //    81,920
    unsigned short* wfl    = ws + 6373376;       //    16,384
    float*          bias_ws = (float*)(ws + 6389760);  // 320 floats

    wcast_kernel<<<20, 64, 0, stream>>>(Wq, bq, Wk, bk, Wv, bv, wfh, wfl, bias_ws);
    proj_kernel<<<dim3(256, BATCH), 256, 0, stream>>>(x, wfh, wfl, bias_ws,
                                                      q_hi, q_lo, k_hi, k_lo, v_frag);
    attn_kernel<<<256, 1024, 0, stream>>>(q_hi, q_lo, k_hi, k_lo, v_frag, x, out);
}

// Round 6
// 151.308 us; speedup vs baseline: 1.1217x; 1.1217x over previous
//
#include <hip/hip_runtime.h>
#include <math.h>

#define CCH   256
#define NPIX  4096
#define BATCH 4

typedef __attribute__((ext_vector_type(8))) short s16x8;
typedef __attribute__((ext_vector_type(4))) short s16x4;
typedef __attribute__((ext_vector_type(4))) float f32x4;

__device__ __forceinline__ unsigned short f2bf(float f) {
    unsigned int u = __float_as_uint(f);
    u += 0x7fff + ((u >> 16) & 1);          // RNE; values are finite
    return (unsigned short)(u >> 16);
}
__device__ __forceinline__ float bf2f(unsigned short h) {
    return __uint_as_float(((unsigned int)h) << 16);
}

// q/k frag (16x16x32 A/B layout), element for (pixel n, dim d):
//   tile = n>>4, lane = (d>>3)*16 + (n&15), elem = d&7
__device__ __forceinline__ size_t qk_addr(int b, int n, int d) {
    return ((((size_t)b * 256 + (n >> 4)) * 64 + ((d >> 3) << 4) + (n & 15)) << 3) + (d & 7);
}
// v frag: standard A-layout for PV; k = j (32-step), m = c (16-tile):
//   tile = (b, j64, c-tile, jj-half), lane = ((j&31)>>3)*16 + (c&15), elem = j&7
__device__ __forceinline__ size_t v_addr(int b, int j, int c) {
    return ((((((size_t)b * 64 + (j >> 6)) * 16 + (c >> 4)) * 2 + ((j >> 5) & 1)) * 64
            + (((j >> 3) & 3) << 4) + (c & 15)) << 3) + (j & 7);
}

// ---------------- W -> A-frag bf16 (hi/lo for q,k; hi for v), once ----------------
__global__ __launch_bounds__(64) void wcast_kernel(
    const float* __restrict__ Wq, const float* __restrict__ bq,
    const float* __restrict__ Wk, const float* __restrict__ bk,
    const float* __restrict__ Wv, const float* __restrict__ bv,
    unsigned short* __restrict__ wfh, unsigned short* __restrict__ wfl,
    float* __restrict__ bias_ws)
{
    const int rt = blockIdx.x;
    const int lane = threadIdx.x, l15 = lane & 15, quad = lane >> 4;
    const float *Ws, *bs; int roff; float scale = 1.0f;
    if (rt < 2)      { Ws = Wq; bs = bq; roff = rt * 16;      scale = 1.44269504f; }
    else if (rt < 4) { Ws = Wk; bs = bk; roff = (rt - 2) * 16; }
    else             { Ws = Wv; bs = bv; roff = (rt - 4) * 16; }

    const float* wrow = Ws + (size_t)(roff + l15) * CCH + quad * 8;
    for (int kb = 0; kb < 8; ++kb) {
        s16x8 h, l;
        #pragma unroll
        for (int d = 0; d < 8; ++d) {
            float wv = wrow[kb * 32 + d] * scale;
            unsigned short hh = f2bf(wv);
            h[d] = (short)hh;
            l[d] = (short)f2bf(wv - bf2f(hh));
        }
        *(s16x8*)&wfh[(((size_t)rt * 8 + kb) * 64 + lane) * 8] = h;
        if (rt < 4) *(s16x8*)&wfl[(((size_t)rt * 8 + kb) * 64 + lane) * 8] = l;
    }
    if (lane < 16) bias_ws[rt * 16 + lane] = bs[roff + lane] * scale;
}

// ---------------- fused cast+projection (loop-inverted, spill-free) ----------------
// kb outermost: only ONE kb's x hi/lo frag is live (8 VGPR) instead of all 8
// (64 VGPR -> scratch spill under the 128-VGPR cap of launch_bounds(256,4)).
// Wave rh owns 1 q/k tile (rt=rh, 24 MFMA) + 4 v tiles (vt=rh*4+i, 32 MFMA):
// balanced 56 MFMA/wave (was 104/40/40/40).
__global__ __launch_bounds__(256, 4) void proj_kernel(
    const float* __restrict__ x,
    const unsigned short* __restrict__ wfh, const unsigned short* __restrict__ wfl,
    const float* __restrict__ bias_ws,
    unsigned short* __restrict__ q_hi, unsigned short* __restrict__ q_lo,
    unsigned short* __restrict__ k_hi, unsigned short* __restrict__ k_lo,
    unsigned short* __restrict__ v_frag)
{
    const int t = threadIdx.x;
    const int rh = t >> 6, lane = t & 63, l15 = lane & 15, quad = lane >> 4;
    const int b = blockIdx.y;
    const int nt = blockIdx.x;

    const float* xb = x + (size_t)b * CCH * NPIX + nt * 16 + l15;

    f32x4 aq0 = {0.f, 0.f, 0.f, 0.f};   // qk hi*hi
    f32x4 aq1 = {0.f, 0.f, 0.f, 0.f};   // qk hi*lo + lo*hi
    f32x4 av[4];                          // v tiles (constant indices via unroll)
    #pragma unroll
    for (int i = 0; i < 4; ++i) av[i] = (f32x4){0.f, 0.f, 0.f, 0.f};

    #pragma unroll 2
    for (int kb = 0; kb < 8; ++kb) {
        s16x8 xh, xl;
        #pragma unroll
        for (int d = 0; d < 8; ++d) {
            float xv = xb[(size_t)(kb * 32 + quad * 8 + d) * NPIX];
            unsigned short h = f2bf(xv);
            xh[d] = (short)h;
            xl[d] = (short)f2bf(xv - bf2f(h));
        }
        // q/k tile rt = rh (3-term hi/lo product)
        {
            const s16x8 ah = *(const s16x8*)&wfh[(((size_t)rh * 8 + kb) * 64 + lane) * 8];
            const s16x8 al = *(const s16x8*)&wfl[(((size_t)rh * 8 + kb) * 64 + lane) * 8];
            aq0 = __builtin_amdgcn_mfma_f32_16x16x32_bf16(ah, xh, aq0, 0, 0, 0);
            aq1 = __builtin_amdgcn_mfma_f32_16x16x32_bf16(ah, xl, aq1, 0, 0, 0);
            aq1 = __builtin_amdgcn_mfma_f32_16x16x32_bf16(al, xh, aq1, 0, 0, 0);
        }
        // v tiles vt = rh*4 + i  (rt = 4 + vt)
        #pragma unroll
        for (int i = 0; i < 4; ++i) {
            const int rt = 4 + rh * 4 + i;
            const s16x8 ah = *(const s16x8*)&wfh[(((size_t)rt * 8 + kb) * 64 + lane) * 8];
            av[i] = __builtin_amdgcn_mfma_f32_16x16x32_bf16(ah, xh, av[i], 0, 0, 0);
        }
    }

    const int n = nt * 16 + l15;
    // ---- q/k store: ushort4 (d&7 consecutive for rr=0..3 at fixed quad) ----
    {
        s16x4 h4, l4;
        #pragma unroll
        for (int rr = 0; rr < 4; ++rr) {
            const int rloc = quad * 4 + rr;
            const float val = aq0[rr] + aq1[rr] + bias_ws[rh * 16 + rloc];
            const unsigned short h = f2bf(val);
            h4[rr] = (short)h;
            l4[rr] = (short)f2bf(val - bf2f(h));
        }
        if (rh < 2) {
            const size_t a = qk_addr(b, n, rh * 16 + quad * 4);
            *(s16x4*)&q_hi[a] = h4;
            *(s16x4*)&q_lo[a] = l4;
        } else {
            const size_t a = qk_addr(b, n, (rh - 2) * 16 + quad * 4);
            *(s16x4*)&k_hi[a] = h4;
            *(s16x4*)&k_lo[a] = l4;
        }
    }
    // ---- v store (scalar: c sits in the lane field, elem = n&7 fixed) ----
    #pragma unroll
    for (int i = 0; i < 4; ++i) {
        const int vt = rh * 4 + i;
        #pragma unroll
        for (int rr = 0; rr < 4; ++rr) {
            const int rloc = quad * 4 + rr;
            const float val = av[i][rr] + bias_ws[(4 + vt) * 16 + rloc];
            v_frag[v_addr(b, n, vt * 16 + rloc)] = f2bf(val);
        }
    }
}

// ---------------- flash attention: R1-proven structure (63.3 us) ----------------
// 512 blocks (2/CU, same batch per XCD) x 8 waves = (jh 0..1, ch 0..3).
// Pipeline: iter t issues V(t) loads + P(t) LDS reads, computes QK(t+1) with
// pre-fetched K regs, writes P(t+1) to the other buffer, prefetches K(t+2),
// then a RAW s_barrier (lgkmcnt(0) only -- global loads stay in flight across
// it), then PV(t) under s_setprio(1).
#define BARRIER_LGKM() do { \
    asm volatile("s_waitcnt lgkmcnt(0)" ::: "memory"); \
    __builtin_amdgcn_s_barrier(); \
    asm volatile("" ::: "memory"); \
} while (0)

#define QK_STEP(KFH, KFL, BUFC) do { \
    f32x4 a0 = __builtin_amdgcn_mfma_f32_16x16x32_bf16((KFH), qfl0, (f32x4){0.f,0.f,0.f,0.f}, 0, 0, 0); \
    a0 = __builtin_amdgcn_mfma_f32_16x16x32_bf16((KFL), qfh0, a0, 0, 0, 0); \
    a0 = __builtin_amdgcn_mfma_f32_16x16x32_bf16((KFH), qfh0, a0, 0, 0, 0); \
    f32x4 a1 = __builtin_amdgcn_mfma_f32_16x16x32_bf16((KFH), qfl1, (f32x4){0.f,0.f,0.f,0.f}, 0, 0, 0); \
    a1 = __builtin_amdgcn_mfma_f32_16x16x32_bf16((KFL), qfh1, a1, 0, 0, 0); \
    a1 = __builtin_amdgcn_mfma_f32_16x16x32_bf16((KFH), qfh1, a1, 0, 0, 0); \
    unsigned int u0 = __float_as_uint(__builtin_exp2f(a0[0])) + 0x8000u; \
    unsigned int u1 = __float_as_uint(__builtin_exp2f(a0[1])) + 0x8000u; \
    unsigned int u2 = __float_as_uint(__builtin_exp2f(a0[2])) + 0x8000u; \
    unsigned int u3 = __float_as_uint(__builtin_exp2f(a0[3])) + 0x8000u; \
    uint2 pv; \
    pv.x = __builtin_amdgcn_perm(u1, u0, 0x07060302u); \
    pv.y = __builtin_amdgcn_perm(u3, u2, 0x07060302u); \
    *(uint2*)&p_lds[jh][BUFC][0 * 2 + pfrag_jj][(prow * 16 + l15) * 8 + pcol] = pv; \
    u0 = __float_as_uint(__builtin_exp2f(a1[0])) + 0x8000u; \
    u1 = __float_as_uint(__builtin_exp2f(a1[1])) + 0x8000u; \
    u2 = __float_as_uint(__builtin_exp2f(a1[2])) + 0x8000u; \
    u3 = __float_as_uint(__builtin_exp2f(a1[3])) + 0x8000u; \
    uint2 pw; \
    pw.x = __builtin_amdgcn_perm(u1, u0, 0x07060302u); \
    pw.y = __builtin_amdgcn_perm(u3, u2, 0x07060302u); \
    *(uint2*)&p_lds[jh][BUFC][1 * 2 + pfrag_jj][(prow * 16 + l15) * 8 + pcol] = pw; \
} while (0)

// One pipelined iteration.  T: current j-step; BUFC: its p_lds buffer (T&1).
// KU_*: K regs holding tile T+1 (consumed by QK).  KL_*: regs to prefetch
// tile T+2 into.  DO_QK: whether a T+1 tile exists.
#define ATTN_BODY(T, BUFC, KU_H, KU_L, KL_H, KL_L, DO_QK) do { \
    const int jt = jh * 32 + (T); \
    /* P(T) frag reads -- latency hidden under QK(T+1) */ \
    const s16x8 pf0 = *(const s16x8*)&p_lds[jh][BUFC][0][lane * 8]; \
    const s16x8 pf1 = *(const s16x8*)&p_lds[jh][BUFC][1][lane * 8]; \
    const s16x8 pf2 = *(const s16x8*)&p_lds[jh][BUFC][2][lane * 8]; \
    const s16x8 pf3 = *(const s16x8*)&p_lds[jh][BUFC][3][lane * 8]; \
    /* V(T) first half: in flight across the barrier */ \
    const size_t vbase = (((size_t)jt * 16 + ch * 4) * 2) * 512; \
    const s16x8 v0 = *(const s16x8*)(vb + vbase); \
    const s16x8 v1 = *(const s16x8*)(vb + vbase + 512); \
    const s16x8 v2 = *(const s16x8*)(vb + vbase + 1024); \
    const s16x8 v3 = *(const s16x8*)(vb + vbase + 1536); \
    if (DO_QK) { QK_STEP(KU_H, KU_L, (BUFC) ^ 1); } \
    /* K(T+2) prefetch (clamped dummy at tail; value unused) */ \
    { \
        const int tpp = ((T) + 2 < 32) ? (T) + 2 : 0; \
        const size_t koff = (size_t)((jh * 32 + tpp) * 4 + ch) * 512; \
        KL_H = *(const s16x8*)(khb + koff); \
        KL_L = *(const s16x8*)(klb + koff); \
    } \
    /* denominator partials: ch0 -> it0 (pf0,pf1), ch1 -> it1 (pf2,pf3) */ \
    if (ch == 0) { \
        lacc = __builtin_amdgcn_mfma_f32_16x16x32_bf16(ones, pf0, lacc, 0, 0, 0); \
        lacc = __builtin_amdgcn_mfma_f32_16x16x32_bf16(ones, pf1, lacc, 0, 0, 0); \
    } else if (ch == 1) { \
        lacc = __builtin_amdgcn_mfma_f32_16x16x32_bf16(ones, pf2, lacc, 0, 0, 0); \
        lacc = __builtin_amdgcn_mfma_f32_16x16x32_bf16(ones, pf3, lacc, 0, 0, 0); \
    } \
    BARRIER_LGKM(); \
    /* V(T) second half (post-barrier to cap register liveness) */ \
    const s16x8 v4 = *(const s16x8*)(vb + vbase + 2048); \
    const s16x8 v5 = *(const s16x8*)(vb + vbase + 2560); \
    const s16x8 v6 = *(const s16x8*)(vb + vbase + 3072); \
    const s16x8 v7 = *(const s16x8*)(vb + vbase + 3584); \
    __builtin_amdgcn_s_setprio(1); \
    acc[0] = __builtin_amdgcn_mfma_f32_16x16x32_bf16(v0, pf0, acc[0], 0, 0, 0); \
    acc[0] = __builtin_amdgcn_mfma_f32_16x16x32_bf16(v1, pf1, acc[0], 0, 0, 0); \
    acc[1] = __builtin_amdgcn_mfma_f32_16x16x32_bf16(v0, pf2, acc[1], 0, 0, 0); \
    acc[1] = __builtin_amdgcn_mfma_f32_16x16x32_bf16(v1, pf3, acc[1], 0, 0, 0); \
    acc[2] = __builtin_amdgcn_mfma_f32_16x16x32_bf16(v2, pf0, acc[2], 0, 0, 0); \
    acc[2] = __builtin_amdgcn_mfma_f32_16x16x32_bf16(v3, pf1, acc[2], 0, 0, 0); \
    acc[3] = __builtin_amdgcn_mfma_f32_16x16x32_bf16(v2, pf2, acc[3], 0, 0, 0); \
    acc[3] = __builtin_amdgcn_mfma_f32_16x16x32_bf16(v3, pf3, acc[3], 0, 0, 0); \
    acc[4] = __builtin_amdgcn_mfma_f32_16x16x32_bf16(v4, pf0, acc[4], 0, 0, 0); \
    acc[4] = __builtin_amdgcn_mfma_f32_16x16x32_bf16(v5, pf1, acc[4], 0, 0, 0); \
    acc[5] = __builtin_amdgcn_mfma_f32_16x16x32_bf16(v4, pf2, acc[5], 0, 0, 0); \
    acc[5] = __builtin_amdgcn_mfma_f32_16x16x32_bf16(v5, pf3, acc[5], 0, 0, 0); \
    acc[6] = __builtin_amdgcn_mfma_f32_16x16x32_bf16(v6, pf0, acc[6], 0, 0, 0); \
    acc[6] = __builtin_amdgcn_mfma_f32_16x16x32_bf16(v7, pf1, acc[6], 0, 0, 0); \
    acc[7] = __builtin_amdgcn_mfma_f32_16x16x32_bf16(v6, pf2, acc[7], 0, 0, 0); \
    acc[7] = __builtin_amdgcn_mfma_f32_16x16x32_bf16(v7, pf3, acc[7], 0, 0, 0); \
    __builtin_amdgcn_s_setprio(0); \
} while (0)

__global__ __launch_bounds__(512, 4) void attn_kernel(
    const unsigned short* __restrict__ q_hi, const unsigned short* __restrict__ q_lo,
    const unsigned short* __restrict__ k_hi, const unsigned short* __restrict__ k_lo,
    const unsigned short* __restrict__ v_frag,
    const float* __restrict__ x, float* __restrict__ out)
{
    __shared__ unsigned short p_lds[2][2][4][512];   // [jh][dbuf][frag][lane*8] = 16 KB
    __shared__ f32x4 comb[2][4][4][64];              // [jh_src][ch][ct][lane] = 32 KB
    __shared__ float lds_l[2][2][16];

    const int t = threadIdx.x;
    const int w = t >> 6, lane = t & 63, l15 = lane & 15, quad = lane >> 4;
    const int jh = w >> 2, ch = w & 3;

    const int f = blockIdx.x;                 // 0..511; XCD-pair per batch
    const int xcd = f & 7;
    const int b = xcd >> 1;
    const int ib = ((xcd & 1) << 6) + (f >> 3);   // i-block 0..127 (32 pixels)

    s16x8 qfh0, qfl0, qfh1, qfl1;
    {
        const size_t qo0 = ((size_t)b * 256 + ib * 2 + 0) * 512 + (size_t)lane * 8;
        const size_t qo1 = ((size_t)b * 256 + ib * 2 + 1) * 512 + (size_t)lane * 8;
        qfh0 = *(const s16x8*)(q_hi + qo0);  qfl0 = *(const s16x8*)(q_lo + qo0);
        qfh1 = *(const s16x8*)(q_hi + qo1);  qfl1 = *(const s16x8*)(q_lo + qo1);
    }

    const s16x8 ones = { (short)0x3F80, (short)0x3F80, (short)0x3F80, (short)0x3F80,
                         (short)0x3F80, (short)0x3F80, (short)0x3F80, (short)0x3F80 };

    f32x4 acc[8];                             // [ct*2+it], constant indices only
    #pragma unroll
    for (int i = 0; i < 8; ++i) acc[i] = (f32x4){0.f, 0.f, 0.f, 0.f};
    f32x4 lacc = {0.f, 0.f, 0.f, 0.f};

    const unsigned short* khb = k_hi + (size_t)b * 131072 + (size_t)lane * 8;
    const unsigned short* klb = k_lo + (size_t)b * 131072 + (size_t)lane * 8;
    const unsigned short* vb  = v_frag + (size_t)b * 1048576 + (size_t)lane * 8;

    const int prow = ((ch & 1) << 1) + (quad >> 1);
    const int pcol = ((quad & 1) << 2);
    const int pfrag_jj = ch >> 1;

    // ---- prologue: K(0) -> QK(0) -> P(0) in buf0; prefetch K(1) ----
    s16x8 ka_h, ka_l, kb_h, kb_l;
    {
        const size_t k0 = (size_t)((jh * 32 + 0) * 4 + ch) * 512;
        ka_h = *(const s16x8*)(khb + k0);
        ka_l = *(const s16x8*)(klb + k0);
    }
    QK_STEP(ka_h, ka_l, 0);
    {
        const size_t k1 = (size_t)((jh * 32 + 1) * 4 + ch) * 512;
        ka_h = *(const s16x8*)(khb + k1);
        ka_l = *(const s16x8*)(klb + k1);
    }
    BARRIER_LGKM();

    #pragma unroll 1
    for (int t2 = 0; t2 < 16; ++t2) {
        ATTN_BODY(2 * t2,     0, ka_h, ka_l, kb_h, kb_l, 1);
        ATTN_BODY(2 * t2 + 1, 1, kb_h, kb_l, ka_h, ka_l, (t2 < 15));
    }

    // ---- epilogue (constant indices inside wave-uniform branches) ----
    if (ch < 2 && lane < 16) lds_l[jh][ch][lane] = lacc[0];
    if (jh == 0) {          // own it0; publish it1
        #pragma unroll
        for (int ct = 0; ct < 4; ++ct)
            comb[0][ch][ct][lane] = acc[ct * 2 + 1];
    } else {                // own it1; publish it0
        #pragma unroll
        for (int ct = 0; ct < 4; ++ct)
            comb[1][ch][ct][lane] = acc[ct * 2 + 0];
    }
    __syncthreads();
    const float linv = 1.f / (lds_l[0][jh][l15] + lds_l[1][jh][l15]);
    const int ibase = (ib * 2 + jh) * 16 + l15;
    #pragma unroll
    for (int ct = 0; ct < 4; ++ct) {
        f32x4 a;
        if (jh == 0) a = acc[ct * 2 + 0];
        else         a = acc[ct * 2 + 1];
        a += comb[1 - jh][ch][ct][lane];
        #pragma unroll
        for (int rr = 0; rr < 4; ++rr) {
            const int c = ch * 64 + ct * 16 + quad * 4 + rr;
            const size_t idx = ((size_t)b * CCH + c) * NPIX + ibase;
            out[idx] = a[rr] * linv + x[idx];
        }
    }
}

extern "C" void kernel_launch(void* const* d_in, const int* in_sizes, int n_in,
                              void* d_out, int out_size, void* d_ws, size_t ws_size,
                              hipStream_t stream) {
    const float* x  = (const float*)d_in[0];
    const float* Wq = (const float*)d_in[1];
    const float* bq = (const float*)d_in[2];
    const float* Wk = (const float*)d_in[3];
    const float* bk = (const float*)d_in[4];
    const float* Wv = (const float*)d_in[5];
    const float* bv = (const float*)d_in[6];
    float* out = (float*)d_out;

    unsigned short* ws = (unsigned short*)d_ws;
    unsigned short* q_hi   = ws;                 //   524,288
    unsigned short* q_lo   = ws + 524288;        //   524,288
    unsigned short* k_hi   = ws + 1048576;       //   524,288
    unsigned short* k_lo   = ws + 1572864;       //   524,288
    unsigned short* v_frag = ws + 2097152;       // 4,194,304
    unsigned short* wfh    = ws + 6291456;       //    81,920
    unsigned short* wfl    = ws + 6373376;       //    16,384
    float*          bias_ws = (float*)(ws + 6389760);  // 320 floats

    wcast_kernel<<<20, 64, 0, stream>>>(Wq, bq, Wk, bk, Wv, bv, wfh, wfl, bias_ws);
    proj_kernel<<<dim3(256, BATCH), 256, 0, stream>>>(x, wfh, wfl, bias_ws,
                                                      q_hi, q_lo, k_hi, k_lo, v_frag);
    attn_kernel<<<512, 512, 0, stream>>>(q_hi, q_lo, k_hi, k_lo, v_frag, x, out);
}